// Round 7
// baseline (272.642 us; speedup 1.0000x reference)
//
#include <hip/hip_runtime.h>
#include <hip/hip_bf16.h>
#include <math.h>

// ---------- helpers ----------
__device__ __forceinline__ unsigned short f2bf(float f) {
    union { float f; unsigned u; } c; c.f = f;
    unsigned r = c.u + 0x7fffu + ((c.u >> 16) & 1u);
    return (unsigned short)(r >> 16);
}
__device__ __forceinline__ float bfu(unsigned short u) {
    union { unsigned x; float f; } c; c.x = ((unsigned)u) << 16; return c.f;
}
__device__ __forceinline__ float gelu_t(float x) {
    float z = x * (1.59576912f + 0.07135481f * x * x);
    return x / (1.0f + __expf(-z));
}

typedef __bf16 bf16x8_t __attribute__((ext_vector_type(8)));
typedef float  f32x4_t  __attribute__((ext_vector_type(4)));
typedef unsigned short u16x8 __attribute__((ext_vector_type(8)));

#define AS1 __attribute__((address_space(1)))
#define AS3 __attribute__((address_space(3)))
__device__ __forceinline__ void g2lds16(const void* g, void* l) {
    __builtin_amdgcn_global_load_lds((const AS1 unsigned int*)g, (AS3 unsigned int*)l, 16, 0, 0);
}

// ---------- weights fp32 -> bf16 in MFMA-FRAGMENT ORDER (R9) ----------
__global__ void cvt_all(const float* __restrict__ wq, const float* __restrict__ wk,
                        const float* __restrict__ wv, const float* __restrict__ wo,
                        const float* __restrict__ w1, const float* __restrict__ w2,
                        const float* __restrict__ ln2g,
                        unsigned short* __restrict__ qkvp, unsigned short* __restrict__ wop,
                        unsigned short* __restrict__ w1p, unsigned short* __restrict__ w2p) {
    int fid = blockIdx.x * 256 + threadIdx.x;   // one 8-elem k-fragment per thread
    const float* src; unsigned short* dst; size_t oidx; int scale = 0; int k0 = 0;
    if (fid < 24576) {           // qkv: n 0..767, kf 0..31
        int n = fid >> 5, kf = fid & 31;
        const float* w = (n < 256) ? wq : (n < 512 ? wk : wv);
        src = w + (size_t)(n & 255) * 256 + kf * 8;
        dst = qkvp;
        oidx = (size_t)(((n >> 7) * 8 + (kf >> 2)) * 4096)
             + ((n >> 4) & 7) * 512 + (kf & 3) * 128 + (n & 15) * 8;
    } else if (fid < 32768) {    // wo: n 0..255
        int fi = fid - 24576;
        int n = fi >> 5, kf = fi & 31;
        src = wo + (size_t)n * 256 + kf * 8;
        dst = wop;
        oidx = (size_t)(((n >> 7) * 8 + (kf >> 2)) * 4096)
             + ((n >> 4) & 7) * 512 + (kf & 3) * 128 + (n & 15) * 8;
    } else if (fid < 65536) {    // w1 (gamma-scaled): n 0..1023
        int fi = fid - 32768;
        int n = fi >> 5, kf = fi & 31;
        src = w1 + (size_t)n * 256 + kf * 8;
        dst = w1p; scale = 1; k0 = kf * 8;
        oidx = (size_t)((n >> 5) * 8192) + (kf >> 2) * 1024 + ((n >> 4) & 1) * 512
             + (kf & 3) * 128 + (n & 15) * 8;
    } else {                     // w2: n 0..255, kf 0..127
        int fi = fid - 65536;
        int n = fi >> 7, kf = fi & 127;
        src = w2 + (size_t)n * 1024 + kf * 8;
        dst = w2p;
        oidx = (size_t)((kf >> 2) * 8192) + (n >> 4) * 512 + (kf & 3) * 128 + (n & 15) * 8;
    }
    float4 a = *(const float4*)(src);
    float4 b = *(const float4*)(src + 4);
    if (scale) {
        float4 g0 = *(const float4*)(ln2g + k0);
        float4 g1 = *(const float4*)(ln2g + k0 + 4);
        a.x *= g0.x; a.y *= g0.y; a.z *= g0.z; a.w *= g0.w;
        b.x *= g1.x; b.y *= g1.y; b.z *= g1.z; b.w *= g1.w;
    }
    u16x8 o = { f2bf(a.x), f2bf(a.y), f2bf(a.z), f2bf(a.w),
                f2bf(b.x), f2bf(b.y), f2bf(b.z), f2bf(b.w) };
    *(u16x8*)(dst + oidx) = o;
}

// ---------- precompute LN2-fold row sums ----------
__global__ void prep_mlp(const float* __restrict__ w1, const float* __restrict__ ln2g,
                         const float* __restrict__ ln2b, const float* __restrict__ b1,
                         float* __restrict__ s1, float* __restrict__ b1p) {
    int n = blockIdx.x * 256 + threadIdx.x;   // 0..1023
    const float* wr = w1 + (size_t)n * 256;
    float ss = 0.f, sb = 0.f;
    #pragma unroll 4
    for (int k = 0; k < 256; k += 4) {
        float4 w = *(const float4*)(wr + k);
        float4 g = *(const float4*)(ln2g + k);
        float4 b = *(const float4*)(ln2b + k);
        ss += w.x * g.x + w.y * g.y + w.z * g.z + w.w * g.w;
        sb += w.x * b.x + w.y * b.y + w.z * b.z + w.w * b.w;
    }
    s1[n] = ss;
    b1p[n] = b1[n] + sb;
}

// ---------- LayerNorm; GATHER=1 fuses shift+window-partition ----------
template<int GATHER, int BF16IN>
__global__ void ln_kernel(const void* __restrict__ xv, const float* __restrict__ g,
                          const float* __restrict__ b, unsigned short* __restrict__ out) {
    int row  = blockIdx.x * 4 + (threadIdx.x >> 6);
    int lane = threadIdx.x & 63;
    int src;
    if (GATHER) {
        int bb = row >> 12;
        int rem = row & 4095;
        int winid = rem >> 6, tok = rem & 63;
        int wi = winid >> 3, wj = winid & 7;
        int ii = tok >> 3,  jj = tok & 7;
        int hh = (wi * 8 + ii + 4) & 63;     // roll(-4)
        int ww = (wj * 8 + jj + 4) & 63;
        src = (bb << 12) + hh * 64 + ww;
    } else {
        src = row;
    }
    float4 v;
    if (BF16IN) {
        ushort4 u = *(const ushort4*)((const unsigned short*)xv + (size_t)src * 256 + lane * 4);
        v.x = bfu(u.x); v.y = bfu(u.y); v.z = bfu(u.z); v.w = bfu(u.w);
    } else {
        v = *(const float4*)((const float*)xv + (size_t)src * 256 + lane * 4);
    }
    float s  = v.x + v.y + v.z + v.w;
    float s2 = v.x*v.x + v.y*v.y + v.z*v.z + v.w*v.w;
    #pragma unroll
    for (int off = 32; off > 0; off >>= 1) {
        s  += __shfl_xor(s,  off, 64);
        s2 += __shfl_xor(s2, off, 64);
    }
    float mean = s * (1.0f / 256.0f);
    float var  = s2 * (1.0f / 256.0f) - mean * mean;
    float rstd = rsqrtf(var + 1e-5f);
    int c0 = lane * 4;
    float4 gg  = *(const float4*)(g + c0);
    float4 bb4 = *(const float4*)(b + c0);
    ushort4 o;
    o.x = f2bf((v.x - mean) * rstd * gg.x + bb4.x);
    o.y = f2bf((v.y - mean) * rstd * gg.y + bb4.y);
    o.z = f2bf((v.z - mean) * rstd * gg.z + bb4.z);
    o.w = f2bf((v.w - mean) * rstd * gg.w + bb4.w);
    *(ushort4*)(out + (size_t)row * 256 + c0) = o;
}

// ---------- tiled MFMA GEMM (QKV / WO): C = A * Bw^T + bias ----------
// 128x128 tile, BK=32 dbuf pipeline, fragment-ordered B, R6 epilogue.
// MODE 0: bf16   MODE 2: window-reverse scatter + fp32 residual -> bf16
template<int MODE, int K>
__global__ __launch_bounds__(256, 4) void gemm_tile(
        const unsigned short* __restrict__ A,
        const unsigned short* __restrict__ Bp,   // fragment-permuted weights
        const float* __restrict__ bias,
        int M, int N,
        unsigned short* __restrict__ obf,
        const void* __restrict__ addp) {
    __shared__ __align__(16) char smem_raw[64 * 132 * 4];   // 33792B
    unsigned short* sm = (unsigned short*)smem_raw;
    float* cst = (float*)smem_raw;
    const int t = threadIdx.x;
    const int lane = t & 63, wave = t >> 6;
    const int m0 = blockIdx.x * 128, n0 = blockIdx.y * 128;
    const int wm = (wave >> 1) * 64, wn = (wave & 1) * 64;
    const int lr = lane & 15, kg = lane >> 4;

    f32x4_t acc[4][4];
    #pragma unroll
    for (int i = 0; i < 4; ++i)
        #pragma unroll
        for (int j = 0; j < 4; ++j) { acc[i][j][0]=0.f; acc[i][j][1]=0.f; acc[i][j][2]=0.f; acc[i][j][3]=0.f; }

    const unsigned short* ga  = A  + (size_t)(m0 + (t >> 2)) * K + (t & 3) * 8;
    const unsigned short* gbp = Bp + (size_t)blockIdx.y * (K / 32) * 4096 + t * 8;
    unsigned short* lA = sm + t * 8;
    unsigned short* lB = sm + 4096 + t * 8;

    const int NT = K / 32;
    g2lds16(ga,                  lA);
    g2lds16(ga + (size_t)64 * K, lA + 2048);
    g2lds16(gbp,                 lB);
    g2lds16(gbp + 2048,          lB + 2048);
    __syncthreads();

    #pragma unroll
    for (int k = 0; k < NT; ++k) {
        const int cur = k & 1;
        if (k + 1 < NT) {
            const int nx = cur ^ 1;
            g2lds16(ga + (k + 1) * 32,                  lA + nx * 8192);
            g2lds16(ga + (size_t)64 * K + (k + 1) * 32, lA + nx * 8192 + 2048);
            g2lds16(gbp + (k + 1) * 4096,               lB + nx * 8192);
            g2lds16(gbp + (k + 1) * 4096 + 2048,        lB + nx * 8192 + 2048);
        }
        const unsigned short* Ab = sm + cur * 8192;
        const unsigned short* Bb = Ab + 4096;
        bf16x8_t af[4], bfr[4];
        #pragma unroll
        for (int i = 0; i < 4; ++i)
            af[i] = *(const bf16x8_t*)&Ab[(wm + i * 16 + lr) * 32 + kg * 8];
        #pragma unroll
        for (int j = 0; j < 4; ++j)
            bfr[j] = *(const bf16x8_t*)&Bb[(((wave & 1) * 4 + j) * 64 + lane) * 8];
        #pragma unroll
        for (int i = 0; i < 4; ++i)
            #pragma unroll
            for (int j = 0; j < 4; ++j)
                acc[i][j] = __builtin_amdgcn_mfma_f32_16x16x32_bf16(af[i], bfr[j], acc[i][j], 0, 0, 0);
        __syncthreads();
    }

    // ---- 2-pass vectorized epilogue, wave-contiguous stores ----
    #pragma unroll
    for (int pass = 0; pass < 2; ++pass) {
        __syncthreads();
        if ((wave >> 1) == pass) {
            float* cw = cst + (kg * 4) * 132 + wn + lr;
            #pragma unroll
            for (int i = 0; i < 4; ++i)
                #pragma unroll
                for (int j = 0; j < 4; ++j)
                    #pragma unroll
                    for (int e = 0; e < 4; ++e)
                        cw[(i * 16 + e) * 132 + j * 16] = acc[i][j][e];
        }
        __syncthreads();
        const int rr = t >> 4;
        const int ch = t & 15;
        if (MODE == 0) {
            #pragma unroll
            for (int c = 0; c < 4; ++c) {
                int r = rr + c * 16;
                int grow = m0 + pass * 64 + r;
                const float* cr = cst + r * 132 + ch * 8;
                const float* bp = bias + n0 + ch * 8;
                float4 a   = *(const float4*)(cr);
                float4 b4  = *(const float4*)(cr + 4);
                float4 ba  = *(const float4*)(bp);
                float4 bb4 = *(const float4*)(bp + 4);
                u16x8 o = { f2bf(a.x + ba.x),  f2bf(a.y + ba.y),  f2bf(a.z + ba.z),  f2bf(a.w + ba.w),
                            f2bf(b4.x + bb4.x), f2bf(b4.y + bb4.y), f2bf(b4.z + bb4.z), f2bf(b4.w + bb4.w) };
                *(u16x8*)(obf + (size_t)grow * N + n0 + ch * 8) = o;
            }
        } else {  // MODE 2
            #pragma unroll
            for (int c = 0; c < 4; ++c) {
                int r = rr + c * 16;
                int grow = m0 + pass * 64 + r;
                int bb_ = grow >> 12, rem = grow & 4095;
                int winid = rem >> 6, tok = rem & 63;
                int wi = winid >> 3, wj = winid & 7;
                int ii = tok >> 3,  jj = tok & 7;
                int hh = (wi * 8 + ii + 4) & 63;   // roll(+4)
                int ww = (wj * 8 + jj + 4) & 63;
                size_t drow = (size_t)(bb_ << 12) + hh * 64 + ww;
                const float* cr = cst + r * 132 + ch * 8;
                const float* bp = bias + n0 + ch * 8;
                const float* res = (const float*)addp + drow * N + n0 + ch * 8;
                float4 a   = *(const float4*)(cr);
                float4 b4  = *(const float4*)(cr + 4);
                float4 ba  = *(const float4*)(bp);
                float4 bb4 = *(const float4*)(bp + 4);
                float4 ra  = *(const float4*)(res);
                float4 rb  = *(const float4*)(res + 4);
                u16x8 o = { f2bf(a.x + ba.x + ra.x),  f2bf(a.y + ba.y + ra.y),
                            f2bf(a.z + ba.z + ra.z),  f2bf(a.w + ba.w + ra.w),
                            f2bf(b4.x + bb4.x + rb.x), f2bf(b4.y + bb4.y + rb.y),
                            f2bf(b4.z + bb4.z + rb.z), f2bf(b4.w + bb4.w + rb.w) };
                *(u16x8*)(obf + drow * N + n0 + ch * 8) = o;
            }
        }
    }
}

// ---------- fused LN2 + MLP-up + GELU + MLP-down + residual ----------
// R11: 256 threads / 4 waves / 64 rows, grid 512 -> 2 BLOCKS/CU = two
// independent barrier domains (R10 showed 8 waves in ONE barrier domain are
// lockstep -> fixed ~7400cy/iter cost un-hideable by intra-block TLP; block B
// computes while block A sits in barrier+vmcnt drain). s1/b1p preloaded to LDS
// (removes per-iter global loads from the gelu chain). Fragment-order LDS
// everywhere (R9, conflict-free). LN folded into w1p/s1/b1p.
// LDS 78336B x2 = 153KB/CU: w1c 2x16KB @0 | w2c 2x16KB @32K | h1c 4x1KB @64K |
// stats 512B @68K | sL 4KB @68.5K | bL 4KB @72.5K.
// Overlays: prologue x-temp [8kk][64r][32k] @0..32K; epilogue cst [32][260] @0.
__global__ __launch_bounds__(256, 2) void fused_mlp(
        const unsigned short* __restrict__ hb,   // [32768][256] bf16 residual state
        const unsigned short* __restrict__ w1p,  // fragment-permuted gamma-scaled w1
        const unsigned short* __restrict__ w2p,  // fragment-permuted w2
        const float* __restrict__ s1,            // [1024]
        const float* __restrict__ b1p,           // [1024]
        const float* __restrict__ b2,            // [256]
        float* __restrict__ out) {               // [32768][256] f32
    extern __shared__ __align__(16) char sm[];
    unsigned short* w1c = (unsigned short*)sm;             // + buf*8192 elems
    unsigned short* w2c = (unsigned short*)(sm + 32768);   // + buf*8192 elems
    unsigned short* h1c = (unsigned short*)(sm + 65536);   // + wave*512 elems
    float* statsLDS = (float*)(sm + 69632);                // [0..63]=rst [64..127]=murs
    float* sL = (float*)(sm + 70144);                      // s1 preload [1024]
    float* bL = (float*)(sm + 74240);                      // b1p preload [1024]
    const int t = threadIdx.x, lane = t & 63, wave = t >> 6;
    const int lr = lane & 15, quad = lane >> 4;
    const size_t rowbase = (size_t)blockIdx.x * 64;

    // ---- prologue: preload s1/b1p; load x, row stats, bounce to A-frags ----
    #pragma unroll
    for (int i = 0; i < 4; ++i) {
        int n = i * 256 + t;
        sL[n] = s1[n];
        bL[n] = b1p[n];
    }
    const int xr = t >> 2, xq = t & 3;                     // row 0..63, quarter 0..3
    {
        const unsigned short* xp = hb + (rowbase + xr) * 256 + xq * 64;
        u16x8 xf[8];
        float s = 0.f, s2 = 0.f;
        #pragma unroll
        for (int f = 0; f < 8; ++f) {
            xf[f] = *(const u16x8*)(xp + f * 8);
            #pragma unroll
            for (int e = 0; e < 8; ++e) { float v = bfu(xf[f][e]); s += v; s2 += v * v; }
        }
        unsigned short* xt = (unsigned short*)sm;          // x-temp [8 kk][64 r][32 k]
        #pragma unroll
        for (int f = 0; f < 8; ++f) {
            int kk = xq * 2 + (f >> 2), kw = (f & 3) * 8;
            *(u16x8*)(xt + kk * 2048 + xr * 32 + kw) = xf[f];
        }
        s  += __shfl_xor(s, 1, 64);  s  += __shfl_xor(s, 2, 64);
        s2 += __shfl_xor(s2, 1, 64); s2 += __shfl_xor(s2, 2, 64);
        if ((t & 3) == 0) {
            float mean = s * (1.0f / 256.0f);
            float var  = s2 * (1.0f / 256.0f) - mean * mean;
            float rst  = rsqrtf(var + 1e-5f);
            statsLDS[xr] = rst;
            statsLDS[64 + xr] = mean * rst;
        }
    }
    __syncthreads();

    bf16x8_t xa[8];
    {
        const unsigned short* xt = (const unsigned short*)sm;
        #pragma unroll
        for (int kk = 0; kk < 8; ++kk)
            xa[kk] = *(const bf16x8_t*)(xt + kk * 2048 + (wave * 16 + lr) * 32 + quad * 8);
    }
    float murs[4], rstv[4];
    #pragma unroll
    for (int e = 0; e < 4; ++e) {
        int r = wave * 16 + quad * 4 + e;
        rstv[e] = statsLDS[r];
        murs[e] = statsLDS[64 + r];
    }
    __syncthreads();   // all x-temp reads done before staging overwrites

    // ---- staging: linear copy of fragment-ordered chunks (256 threads) ----
    auto stage = [&](int c, int buf) {
        #pragma unroll
        for (int i = 0; i < 4; ++i) {
            g2lds16(w1p + (size_t)c * 8192 + i * 2048 + t * 8, w1c + buf * 8192 + i * 2048 + t * 8);
            g2lds16(w2p + (size_t)c * 8192 + i * 2048 + t * 8, w2c + buf * 8192 + i * 2048 + t * 8);
        }
    };
    stage(0, 0);

    f32x4_t zz[16];
    #pragma unroll
    for (int cs = 0; cs < 16; ++cs) { zz[cs][0]=0.f; zz[cs][1]=0.f; zz[cs][2]=0.f; zz[cs][3]=0.f; }
    __syncthreads();   // buf0 staged

    unsigned short* H = h1c + wave * 512;   // fragment order [4 qk][16 r][8 k]
    for (int c = 0; c < 32; ++c) {
        const int cur = c & 1;
        if (c + 1 < 32) stage(c + 1, cur ^ 1);
        const unsigned short* W1 = w1c + cur * 8192;
        const unsigned short* W2 = w2c + cur * 8192;
        // per-iter bias terms from LDS (off the global-latency path)
        float s1v[2], b1v[2];
        #pragma unroll
        for (int ns = 0; ns < 2; ++ns) {
            int col = c * 32 + ns * 16 + lr;
            s1v[ns] = sL[col];
            b1v[ns] = bL[col];
        }
        // GEMM1: 16 rows x 32 hidden, K=256 (A from regs; B reads contiguous)
        f32x4_t a1[2];
        #pragma unroll
        for (int ns = 0; ns < 2; ++ns) { a1[ns][0]=0.f; a1[ns][1]=0.f; a1[ns][2]=0.f; a1[ns][3]=0.f; }
        #pragma unroll
        for (int kk = 0; kk < 8; ++kk) {
            bf16x8_t b0  = *(const bf16x8_t*)&W1[kk * 1024 + lane * 8];
            bf16x8_t b1f = *(const bf16x8_t*)&W1[kk * 1024 + 512 + lane * 8];
            a1[0] = __builtin_amdgcn_mfma_f32_16x16x32_bf16(xa[kk], b0,  a1[0], 0, 0, 0);
            a1[1] = __builtin_amdgcn_mfma_f32_16x16x32_bf16(xa[kk], b1f, a1[1], 0, 0, 0);
        }
        // LN-fold + bias + gelu -> bf16 -> wave-local H (fragment order)
        #pragma unroll
        for (int ns = 0; ns < 2; ++ns)
            #pragma unroll
            for (int e = 0; e < 4; ++e) {
                float h = rstv[e] * a1[ns][e] - murs[e] * s1v[ns] + b1v[ns];
                H[(ns * 2 + (lr >> 3)) * 128 + (quad * 4 + e) * 8 + (lr & 7)] = f2bf(gelu_t(h));
            }
        __asm__ volatile("s_waitcnt lgkmcnt(0)" ::: "memory");
        // GEMM2: 16 rows x 256 out, K=32 (accumulate; all reads contiguous)
        bf16x8_t pa = *(const bf16x8_t*)&H[lane * 8];
        #pragma unroll
        for (int cs = 0; cs < 16; ++cs) {
            bf16x8_t vb = *(const bf16x8_t*)&W2[cs * 512 + lane * 8];
            zz[cs] = __builtin_amdgcn_mfma_f32_16x16x32_bf16(pa, vb, zz[cs], 0, 0, 0);
        }
        __syncthreads();   // next-buf staged (drained) + all reads of cur done
    }

    // ---- epilogue: z + b2 + residual -> fp32 out (2 passes via LDS [32][260]) ----
    float* cst = (float*)sm;
    #pragma unroll
    for (int pass = 0; pass < 2; ++pass) {
        __syncthreads();
        if ((wave >> 1) == pass) {   // waves 2p,2p+1 own rows [pass*32, pass*32+32)
            #pragma unroll
            for (int cs = 0; cs < 16; ++cs)
                #pragma unroll
                for (int e = 0; e < 4; ++e)
                    cst[((wave & 1) * 16 + quad * 4 + e) * 260 + cs * 16 + lr] = zz[cs][e];
        }
        __syncthreads();
        const int r = t >> 3, q = t & 7;     // row 0..31, 32-col chunk 0..7
        size_t grow = rowbase + pass * 32 + r;
        const float* cr = cst + r * 260 + q * 32;
        const unsigned short* rp = hb + grow * 256 + q * 32;
        float* op = out + grow * 256 + q * 32;
        #pragma unroll
        for (int c4 = 0; c4 < 8; ++c4) {
            float4 a  = *(const float4*)(cr + c4 * 4);
            float4 bb = *(const float4*)(b2 + q * 32 + c4 * 4);
            ushort4 rv = *(const ushort4*)(rp + c4 * 4);
            float4 o = { a.x + bb.x + bfu(rv.x), a.y + bb.y + bfu(rv.y),
                         a.z + bb.z + bfu(rv.z), a.w + bb.w + bfu(rv.w) };
            *(float4*)(op + c4 * 4) = o;
        }
    }
}

// ---------- MFMA attention: 4 waves/block, each wave one (window-batch, head) ----------
#define PR 72
#define VR 72
__global__ void __launch_bounds__(256) attn_mfma(
        const unsigned short* __restrict__ qkv,
        const float* __restrict__ relt,
        unsigned short* __restrict__ ctx) {
    __shared__ float rs[1800];
    __shared__ unsigned short Pl[4][64 * PR];
    __shared__ unsigned short Vt[4][32 * VR];

    int t = threadIdx.x;
    int lane = t & 63, wave = t >> 6;
    for (int i = t; i < 1800; i += 256) rs[i] = relt[i];
    __syncthreads();

    int wh = blockIdx.x * 4 + wave;
    int wg = wh >> 3, h = wh & 7;
    int win = wg & 63;
    int ln = lane & 15, quad = lane >> 4;

    unsigned short* P = &Pl[wave][0];
    unsigned short* V = &Vt[wave][0];
    const unsigned short* base = qkv + (size_t)wg * 64 * 768 + h * 32;

    union BF8 { bf16x8_t v; unsigned short s[8]; };
    {
        const bf16x8_t* vp = (const bf16x8_t*)(base + (size_t)lane * 768 + 512);
        BF8 vv[4];
        #pragma unroll
        for (int c = 0; c < 4; ++c) vv[c].v = vp[c];
        #pragma unroll
        for (int c = 0; c < 4; ++c)
            #pragma unroll
            for (int e = 0; e < 8; ++e)
                V[(c * 8 + e) * VR + lane] = vv[c].s[e];
    }

    bf16x8_t qa[4], kb[4];
    #pragma unroll
    for (int i = 0; i < 4; ++i)
        qa[i] = *(const bf16x8_t*)(base + (size_t)(i * 16 + ln) * 768 + quad * 8);
    #pragma unroll
    for (int j = 0; j < 4; ++j)
        kb[j] = *(const bf16x8_t*)(base + (size_t)(j * 16 + ln) * 768 + 256 + quad * 8);

    f32x4_t acc[4][4];
    #pragma unroll
    for (int i = 0; i < 4; ++i)
        #pragma unroll
        for (int j = 0; j < 4; ++j) { acc[i][j][0]=0.f; acc[i][j][1]=0.f; acc[i][j][2]=0.f; acc[i][j][3]=0.f; }
    #pragma unroll
    for (int i = 0; i < 4; ++i)
        #pragma unroll
        for (int j = 0; j < 4; ++j)
            acc[i][j] = __builtin_amdgcn_mfma_f32_16x16x32_bf16(qa[i], kb[j], acc[i][j], 0, 0, 0);

    const float scale = 0.17677669529663687f;
    int wi = win >> 3, wj = win & 7;
    int mjv = ln & 7;
    int regm[4], mi[4];
    #pragma unroll
    for (int j = 0; j < 4; ++j) {
        mi[j] = j * 2 + (ln >> 3);
        int hm = wi * 8 + mi[j], wm = wj * 8 + mjv;
        regm[j] = (hm < 56 ? 0 : (hm < 60 ? 1 : 2)) * 3 + (wm < 56 ? 0 : (wm < 60 ? 1 : 2));
    }
    float inv[4][4];
    #pragma unroll
    for (int i = 0; i < 4; ++i) {
        #pragma unroll
        for (int e = 0; e < 4; ++e) {
            int q = i * 16 + quad * 4 + e;
            int ti = q >> 3, tj = q & 7;
            int hn = wi * 8 + ti, wn = wj * 8 + tj;
            int regn = (hn < 56 ? 0 : (hn < 60 ? 1 : 2)) * 3 + (wn < 56 ? 0 : (wn < 60 ? 1 : 2));
            float sum = 0.f;
            #pragma unroll
            for (int j = 0; j < 4; ++j) {
                float bv = rs[((ti - mi[j] + 7) * 15 + (tj - mjv + 7)) * 8 + h];
                float sv = acc[i][j][e] * scale + bv + (regm[j] != regn ? -100.f : 0.f);
                float p = __expf(sv);
                sum += p;
                P[q * PR + j * 16 + ln] = f2bf(p);
            }
            #pragma unroll
            for (int off = 1; off < 16; off <<= 1) sum += __shfl_xor(sum, off, 64);
            inv[i][e] = 1.0f / sum;
        }
    }
    __syncthreads();

    bf16x8_t vb[2][2];
    #pragma unroll
    for (int jd = 0; jd < 2; ++jd)
        #pragma unroll
        for (int kc = 0; kc < 2; ++kc)
            vb[jd][kc] = *(const bf16x8_t*)&V[(jd * 16 + ln) * VR + kc * 32 + quad * 8];
    f32x4_t occ[4][2];
    #pragma unroll
    for (int i = 0; i < 4; ++i)
        #pragma unroll
        for (int jd = 0; jd < 2; ++jd) { occ[i][jd][0]=0.f; occ[i][jd][1]=0.f; occ[i][jd][2]=0.f; occ[i][jd][3]=0.f; }
    #pragma unroll
    for (int i = 0; i < 4; ++i) {
        #pragma unroll
        for (int kc = 0; kc < 2; ++kc) {
            bf16x8_t pf = *(const bf16x8_t*)&P[(i * 16 + ln) * PR + kc * 32 + quad * 8];
            occ[i][0] = __builtin_amdgcn_mfma_f32_16x16x32_bf16(pf, vb[0][kc], occ[i][0], 0, 0, 0);
            occ[i][1] = __builtin_amdgcn_mfma_f32_16x16x32_bf16(pf, vb[1][kc], occ[i][1], 0, 0, 0);
        }
    }

    unsigned short* cbase = ctx + (size_t)wg * 64 * 256 + h * 32;
    #pragma unroll
    for (int i = 0; i < 4; ++i)
        #pragma unroll
        for (int e = 0; e < 4; ++e) {
            int q = i * 16 + quad * 4 + e;
            #pragma unroll
            for (int jd = 0; jd < 2; ++jd)
                cbase[(size_t)q * 256 + jd * 16 + ln] = f2bf(occ[i][jd][e] * inv[i][e]);
        }
}

// ---------- launch ----------
extern "C" void kernel_launch(void* const* d_in, const int* in_sizes, int n_in,
                              void* d_out, int out_size, void* d_ws, size_t ws_size,
                              hipStream_t stream) {
    const float* hs   = (const float*)d_in[0];
    const float* ln1g = (const float*)d_in[1];
    const float* ln1b = (const float*)d_in[2];
    const float* wq   = (const float*)d_in[3];
    const float* bq   = (const float*)d_in[4];
    const float* wk   = (const float*)d_in[5];
    const float* bk   = (const float*)d_in[6];
    const float* wv   = (const float*)d_in[7];
    const float* bv   = (const float*)d_in[8];
    const float* relt = (const float*)d_in[9];
    const float* wo   = (const float*)d_in[10];
    const float* bo   = (const float*)d_in[11];
    const float* ln2g = (const float*)d_in[12];
    const float* ln2b = (const float*)d_in[13];
    const float* w1   = (const float*)d_in[14];
    const float* b1   = (const float*)d_in[15];
    const float* w2   = (const float*)d_in[16];
    const float* b2   = (const float*)d_in[17];
    float* out = (float*)d_out;

    const size_t NTOK = 32768;
    size_t off = 0;
    auto carve = [&](size_t bytes) { void* p = (char*)d_ws + off; off += (bytes + 255) & ~(size_t)255; return p; };
    unsigned short* wqkv_p = (unsigned short*)carve(768ull * 256 * 2);
    unsigned short* wo_p   = (unsigned short*)carve(65536ull * 2);
    unsigned short* w1p    = (unsigned short*)carve(262144ull * 2);   // fragment-order, gamma-scaled
    unsigned short* w2p    = (unsigned short*)carve(262144ull * 2);   // fragment-order
    float*          bqkv   = (float*)carve(768ull * 4);
    float*          s1w    = (float*)carve(1024ull * 4);
    float*          b1w    = (float*)carve(1024ull * 4);
    unsigned short* hiddenb= (unsigned short*)carve(NTOK * 256 * 2);  // bf16 residual state
    unsigned short* xw     = (unsigned short*)carve(NTOK * 256 * 2);
    unsigned short* qkvb   = (unsigned short*)carve(NTOK * 768 * 2);  // q|k|v
    unsigned short* cx     = (unsigned short*)carve(NTOK * 256 * 2);

    static bool attr_set = false;
    if (!attr_set) {
        hipFuncSetAttribute(reinterpret_cast<const void*>(fused_mlp),
                            hipFuncAttributeMaxDynamicSharedMemorySize, 78336);
        attr_set = true;
    }

    // 1) weights -> bf16 fragment order (w1 gamma-folded); biases; LN2-fold sums
    cvt_all<<<384, 256, 0, stream>>>(wq, wk, wv, wo, w1, w2, ln2g, wqkv_p, wo_p, w1p, w2p);
    prep_mlp<<<4, 256, 0, stream>>>(w1, ln2g, ln2b, b1, s1w, b1w);
    hipMemcpyAsync(bqkv,       bq, 256 * 4, hipMemcpyDeviceToDevice, stream);
    hipMemcpyAsync(bqkv + 256, bk, 256 * 4, hipMemcpyDeviceToDevice, stream);
    hipMemcpyAsync(bqkv + 512, bv, 256 * 4, hipMemcpyDeviceToDevice, stream);

    // 2) LN1 + cyclic shift + window partition -> xw (bf16)
    ln_kernel<1, 0><<<8192, 256, 0, stream>>>(hs, ln1g, ln1b, xw);

    // 3) fused QKV projection
    gemm_tile<0, 256><<<dim3(256, 6), 256, 0, stream>>>(xw, wqkv_p, bqkv, 32768, 768, qkvb, nullptr);

    // 4) windowed MFMA attention
    attn_mfma<<<1024, 256, 0, stream>>>(qkvb, relt, cx);

    // 5) out projection + window reverse + unshift + fp32 residual -> hiddenb (bf16)
    gemm_tile<2, 256><<<dim3(256, 2), 256, 0, stream>>>(cx, wo_p, bo, 32768, 256, hiddenb, hs);

    // 6-8) fused LN2 + MLP (up+gelu+down) + residual -> out (fp32)
    fused_mlp<<<512, 256, 78336, stream>>>(hiddenb, w1p, w2p, s1w, b1w, b2, out);
}

// Round 9
// 246.079 us; speedup vs baseline: 1.1079x; 1.1079x over previous
//
#include <hip/hip_runtime.h>
#include <hip/hip_bf16.h>
#include <math.h>

// ---------- helpers ----------
__device__ __forceinline__ unsigned short f2bf(float f) {
    union { float f; unsigned u; } c; c.f = f;
    unsigned r = c.u + 0x7fffu + ((c.u >> 16) & 1u);
    return (unsigned short)(r >> 16);
}
__device__ __forceinline__ float bfu(unsigned short u) {
    union { unsigned x; float f; } c; c.x = ((unsigned)u) << 16; return c.f;
}
__device__ __forceinline__ float gelu_t(float x) {
    float z = x * (1.59576912f + 0.07135481f * x * x);
    return x / (1.0f + __expf(-z));
}

typedef __bf16 bf16x8_t __attribute__((ext_vector_type(8)));
typedef float  f32x4_t  __attribute__((ext_vector_type(4)));
typedef unsigned short u16x8 __attribute__((ext_vector_type(8)));

#define AS1 __attribute__((address_space(1)))
#define AS3 __attribute__((address_space(3)))
__device__ __forceinline__ void g2lds16(const void* g, void* l) {
    __builtin_amdgcn_global_load_lds((const AS1 unsigned int*)g, (AS3 unsigned int*)l, 16, 0, 0);
}

// ---------- weights fp32 -> bf16, unified MFMA-fragment order; +bias packing ----------
// Per 128-col x 32-k chunk: lane L's 16B B-fragment at chunk*8192B + L*16B
// -> every weight ds_read_b128 is a contiguous 1024B wave-span (conflict-free, R9).
// oidx = ((n>>7)*(K/32) + (kf>>2))*4096 + ((n>>4)&7)*512 + (kf&3)*128 + (n&15)*8
// Block 384 packs bqkv = [bq|bk|bv] (folds 3 D2D blits into this launch — R13).
__global__ void cvt_all(const float* __restrict__ wq, const float* __restrict__ wk,
                        const float* __restrict__ wv, const float* __restrict__ wo,
                        const float* __restrict__ w1, const float* __restrict__ w2,
                        const float* __restrict__ bq, const float* __restrict__ bk,
                        const float* __restrict__ bv, float* __restrict__ bqkv,
                        unsigned short* __restrict__ qkvp, unsigned short* __restrict__ wop,
                        unsigned short* __restrict__ w1p, unsigned short* __restrict__ w2p) {
    int fid = blockIdx.x * 256 + threadIdx.x;   // one 8-elem k-fragment per thread; 98304 weight frags
    if (fid >= 98304) {                          // bias block
        int i = fid - 98304;
        if (i < 768) bqkv[i] = (i < 256) ? bq[i] : (i < 512 ? bk[i - 256] : bv[i - 512]);
        return;
    }
    const float* src; unsigned short* dst; int n, kf, KC;
    if (fid < 24576) {           // qkv: n 0..767, K=256
        n = fid >> 5; kf = fid & 31; KC = 8;
        const float* w = (n < 256) ? wq : (n < 512 ? wk : wv);
        src = w + (size_t)(n & 255) * 256 + kf * 8; dst = qkvp;
    } else if (fid < 32768) {    // wo: n 0..255, K=256
        int fi = fid - 24576; n = fi >> 5; kf = fi & 31; KC = 8;
        src = wo + (size_t)n * 256 + kf * 8; dst = wop;
    } else if (fid < 65536) {    // w1: n 0..1023, K=256
        int fi = fid - 32768; n = fi >> 5; kf = fi & 31; KC = 8;
        src = w1 + (size_t)n * 256 + kf * 8; dst = w1p;
    } else {                     // w2: n 0..255, K=1024
        int fi = fid - 65536; n = fi >> 7; kf = fi & 127; KC = 32;
        src = w2 + (size_t)n * 1024 + kf * 8; dst = w2p;
    }
    size_t oidx = (size_t)(((n >> 7) * KC + (kf >> 2)) * 4096)
                + ((n >> 4) & 7) * 512 + (kf & 3) * 128 + (n & 15) * 8;
    float4 a = *(const float4*)(src);
    float4 b = *(const float4*)(src + 4);
    u16x8 o = { f2bf(a.x), f2bf(a.y), f2bf(a.z), f2bf(a.w),
                f2bf(b.x), f2bf(b.y), f2bf(b.z), f2bf(b.w) };
    *(u16x8*)(dst + oidx) = o;
}

// ---------- LayerNorm; GATHER=1 fuses shift+window-partition ----------
template<int GATHER, int BF16IN>
__global__ void ln_kernel(const void* __restrict__ xv, const float* __restrict__ g,
                          const float* __restrict__ b, unsigned short* __restrict__ out) {
    int row  = blockIdx.x * 4 + (threadIdx.x >> 6);
    int lane = threadIdx.x & 63;
    int src;
    if (GATHER) {
        int bb = row >> 12;
        int rem = row & 4095;
        int winid = rem >> 6, tok = rem & 63;
        int wi = winid >> 3, wj = winid & 7;
        int ii = tok >> 3,  jj = tok & 7;
        int hh = (wi * 8 + ii + 4) & 63;     // roll(-4)
        int ww = (wj * 8 + jj + 4) & 63;
        src = (bb << 12) + hh * 64 + ww;
    } else {
        src = row;
    }
    float4 v;
    if (BF16IN) {
        ushort4 u = *(const ushort4*)((const unsigned short*)xv + (size_t)src * 256 + lane * 4);
        v.x = bfu(u.x); v.y = bfu(u.y); v.z = bfu(u.z); v.w = bfu(u.w);
    } else {
        v = *(const float4*)((const float*)xv + (size_t)src * 256 + lane * 4);
    }
    float s  = v.x + v.y + v.z + v.w;
    float s2 = v.x*v.x + v.y*v.y + v.z*v.z + v.w*v.w;
    #pragma unroll
    for (int off = 32; off > 0; off >>= 1) {
        s  += __shfl_xor(s,  off, 64);
        s2 += __shfl_xor(s2, off, 64);
    }
    float mean = s * (1.0f / 256.0f);
    float var  = s2 * (1.0f / 256.0f) - mean * mean;
    float rstd = rsqrtf(var + 1e-5f);
    int c0 = lane * 4;
    float4 gg  = *(const float4*)(g + c0);
    float4 bb4 = *(const float4*)(b + c0);
    ushort4 o;
    o.x = f2bf((v.x - mean) * rstd * gg.x + bb4.x);
    o.y = f2bf((v.y - mean) * rstd * gg.y + bb4.y);
    o.z = f2bf((v.z - mean) * rstd * gg.z + bb4.z);
    o.w = f2bf((v.w - mean) * rstd * gg.w + bb4.w);
    *(ushort4*)(out + (size_t)row * 256 + c0) = o;
}

// ---------- tiled MFMA GEMM: C[M,N] = A[M,K] * Bw[N,K]^T + bias ----------
// R13: reverted to the PROVEN 2-buffer BK=32 __syncthreads pipeline (R7/R11 —
// 3 rounds correct). R12's counted-vmcnt raw-barrier raced (issued-not-completed
// ds_read vs async g2lds overwrite) and m131 says counted vmcnt is neutral on
// this 2-phase structure anyway. Fragment-ordered B (R9, conflict-free
// ds_read_b128); R6 wave-contiguous vectorized epilogue (WRITE_SIZE = ideal).
// MODE 0: bf16  MODE 1: gelu->bf16  MODE 2: scatter+fp32 residual->bf16
// MODE 3: bf16 residual -> fp32 out
template<int MODE, int K>
__global__ __launch_bounds__(256, 4) void gemm_tile(
        const unsigned short* __restrict__ A,
        const unsigned short* __restrict__ Bp,   // fragment-permuted weights
        const float* __restrict__ bias,
        int M, int N,
        unsigned short* __restrict__ obf,
        float* __restrict__ of32,
        const void* __restrict__ addp) {
    __shared__ __align__(16) char smem_raw[64 * 132 * 4];   // 33792B: dbuf 32KB / C-stage overlay
    unsigned short* sm = (unsigned short*)smem_raw;
    float* cst = (float*)smem_raw;
    const int t = threadIdx.x;
    const int lane = t & 63, wave = t >> 6;
    const int m0 = blockIdx.x * 128, n0 = blockIdx.y * 128;
    const int wm = (wave >> 1) * 64, wn = (wave & 1) * 64;
    const int lr = lane & 15, kg = lane >> 4;

    f32x4_t acc[4][4];
    #pragma unroll
    for (int i = 0; i < 4; ++i)
        #pragma unroll
        for (int j = 0; j < 4; ++j) { acc[i][j][0]=0.f; acc[i][j][1]=0.f; acc[i][j][2]=0.f; acc[i][j][3]=0.f; }

    const unsigned short* ga  = A  + (size_t)(m0 + (t >> 2)) * K + (t & 3) * 8;
    const unsigned short* gbp = Bp + (size_t)blockIdx.y * (K / 32) * 4096 + t * 8;
    unsigned short* lA = sm + t * 8;
    unsigned short* lB = sm + 4096 + t * 8;

    const int NT = K / 32;
    g2lds16(ga,                  lA);
    g2lds16(ga + (size_t)64 * K, lA + 2048);
    g2lds16(gbp,                 lB);
    g2lds16(gbp + 2048,          lB + 2048);
    __syncthreads();

    #pragma unroll
    for (int k = 0; k < NT; ++k) {
        const int cur = k & 1;
        if (k + 1 < NT) {
            const int nx = cur ^ 1;
            g2lds16(ga + (k + 1) * 32,                  lA + nx * 8192);
            g2lds16(ga + (size_t)64 * K + (k + 1) * 32, lA + nx * 8192 + 2048);
            g2lds16(gbp + (size_t)(k + 1) * 4096,        lB + nx * 8192);
            g2lds16(gbp + (size_t)(k + 1) * 4096 + 2048, lB + nx * 8192 + 2048);
        }
        const unsigned short* Ab = sm + cur * 8192;
        const unsigned short* Bb = Ab + 4096;
        bf16x8_t af[4], bfr[4];
        #pragma unroll
        for (int i = 0; i < 4; ++i)
            af[i] = *(const bf16x8_t*)&Ab[(wm + i * 16 + lr) * 32 + kg * 8];
        #pragma unroll
        for (int j = 0; j < 4; ++j)
            bfr[j] = *(const bf16x8_t*)&Bb[(((wave & 1) * 4 + j) * 64 + lane) * 8];
        #pragma unroll
        for (int i = 0; i < 4; ++i)
            #pragma unroll
            for (int j = 0; j < 4; ++j)
                acc[i][j] = __builtin_amdgcn_mfma_f32_16x16x32_bf16(af[i], bfr[j], acc[i][j], 0, 0, 0);
        __syncthreads();
    }

    // ---- 2-pass vectorized epilogue, wave-contiguous stores (R6) ----
    #pragma unroll
    for (int pass = 0; pass < 2; ++pass) {
        if (pass) __syncthreads();
        if ((wave >> 1) == pass) {
            float* cw = cst + (kg * 4) * 132 + wn + lr;
            #pragma unroll
            for (int i = 0; i < 4; ++i)
                #pragma unroll
                for (int j = 0; j < 4; ++j)
                    #pragma unroll
                    for (int e = 0; e < 4; ++e)
                        cw[(i * 16 + e) * 132 + j * 16] = acc[i][j][e];
        }
        __syncthreads();
        const int rr = t >> 4;
        const int ch = t & 15;
        if (MODE == 0 || MODE == 1) {
            #pragma unroll
            for (int c = 0; c < 4; ++c) {
                int r = rr + c * 16;
                int grow = m0 + pass * 64 + r;
                const float* cr = cst + r * 132 + ch * 8;
                const float* bp = bias + n0 + ch * 8;
                float4 a   = *(const float4*)(cr);
                float4 b4  = *(const float4*)(cr + 4);
                float4 ba  = *(const float4*)(bp);
                float4 bb4 = *(const float4*)(bp + 4);
                float x0 = a.x + ba.x,  x1 = a.y + ba.y,  x2 = a.z + ba.z,  x3 = a.w + ba.w;
                float x4 = b4.x + bb4.x, x5 = b4.y + bb4.y, x6 = b4.z + bb4.z, x7 = b4.w + bb4.w;
                if (MODE == 1) {
                    x0 = gelu_t(x0); x1 = gelu_t(x1); x2 = gelu_t(x2); x3 = gelu_t(x3);
                    x4 = gelu_t(x4); x5 = gelu_t(x5); x6 = gelu_t(x6); x7 = gelu_t(x7);
                }
                u16x8 o = { f2bf(x0), f2bf(x1), f2bf(x2), f2bf(x3),
                            f2bf(x4), f2bf(x5), f2bf(x6), f2bf(x7) };
                *(u16x8*)(obf + (size_t)grow * N + n0 + ch * 8) = o;
            }
        } else if (MODE == 2) {
            #pragma unroll
            for (int c = 0; c < 4; ++c) {
                int r = rr + c * 16;
                int grow = m0 + pass * 64 + r;
                int bb_ = grow >> 12, rem = grow & 4095;
                int winid = rem >> 6, tok = rem & 63;
                int wi = winid >> 3, wj = winid & 7;
                int ii = tok >> 3,  jj = tok & 7;
                int hh = (wi * 8 + ii + 4) & 63;   // roll(+4)
                int ww = (wj * 8 + jj + 4) & 63;
                size_t drow = (size_t)(bb_ << 12) + hh * 64 + ww;
                const float* cr = cst + r * 132 + ch * 8;
                const float* bp = bias + n0 + ch * 8;
                const float* res = (const float*)addp + drow * N + n0 + ch * 8;
                float4 a   = *(const float4*)(cr);
                float4 b4  = *(const float4*)(cr + 4);
                float4 ba  = *(const float4*)(bp);
                float4 bb4 = *(const float4*)(bp + 4);
                float4 ra  = *(const float4*)(res);
                float4 rb  = *(const float4*)(res + 4);
                u16x8 o = { f2bf(a.x + ba.x + ra.x),  f2bf(a.y + ba.y + ra.y),
                            f2bf(a.z + ba.z + ra.z),  f2bf(a.w + ba.w + ra.w),
                            f2bf(b4.x + bb4.x + rb.x), f2bf(b4.y + bb4.y + rb.y),
                            f2bf(b4.z + bb4.z + rb.z), f2bf(b4.w + bb4.w + rb.w) };
                *(u16x8*)(obf + drow * N + n0 + ch * 8) = o;
            }
        } else {  // MODE 3: fp32 out + bf16 residual
            #pragma unroll
            for (int c = 0; c < 8; ++c) {
                int r = rr + (c & 3) * 16;
                int grow = m0 + pass * 64 + r;
                int chunk = ch + (c >> 2) * 16;    // 0..31: float4 index within 128-col segment
                const float* cr = cst + r * 132 + chunk * 4;
                const float* bp = bias + n0 + chunk * 4;
                const unsigned short* res = (const unsigned short*)addp + (size_t)grow * N + n0 + chunk * 4;
                float4 a  = *(const float4*)(cr);
                float4 ba = *(const float4*)(bp);
                ushort4 rv = *(const ushort4*)(res);
                float4 o1 = { bfu(rv.x) + a.x + ba.x,  bfu(rv.y) + a.y + ba.y,
                              bfu(rv.z) + a.z + ba.z,  bfu(rv.w) + a.w + ba.w };
                *(float4*)(of32 + (size_t)grow * N + n0 + chunk * 4) = o1;
            }
        }
    }
}

// ---------- MFMA attention: 4 waves/block, each wave one (window-batch, head) ----------
#define PR 72
#define VR 72
__global__ void __launch_bounds__(256) attn_mfma(
        const unsigned short* __restrict__ qkv,
        const float* __restrict__ relt,
        unsigned short* __restrict__ ctx) {
    __shared__ float rs[1800];
    __shared__ unsigned short Pl[4][64 * PR];
    __shared__ unsigned short Vt[4][32 * VR];

    int t = threadIdx.x;
    int lane = t & 63, wave = t >> 6;
    for (int i = t; i < 1800; i += 256) rs[i] = relt[i];
    __syncthreads();

    int wh = blockIdx.x * 4 + wave;
    int wg = wh >> 3, h = wh & 7;
    int win = wg & 63;
    int ln = lane & 15, quad = lane >> 4;

    unsigned short* P = &Pl[wave][0];
    unsigned short* V = &Vt[wave][0];
    const unsigned short* base = qkv + (size_t)wg * 64 * 768 + h * 32;

    union BF8 { bf16x8_t v; unsigned short s[8]; };
    {
        const bf16x8_t* vp = (const bf16x8_t*)(base + (size_t)lane * 768 + 512);
        BF8 vv[4];
        #pragma unroll
        for (int c = 0; c < 4; ++c) vv[c].v = vp[c];
        #pragma unroll
        for (int c = 0; c < 4; ++c)
            #pragma unroll
            for (int e = 0; e < 8; ++e)
                V[(c * 8 + e) * VR + lane] = vv[c].s[e];
    }

    bf16x8_t qa[4], kb[4];
    #pragma unroll
    for (int i = 0; i < 4; ++i)
        qa[i] = *(const bf16x8_t*)(base + (size_t)(i * 16 + ln) * 768 + quad * 8);
    #pragma unroll
    for (int j = 0; j < 4; ++j)
        kb[j] = *(const bf16x8_t*)(base + (size_t)(j * 16 + ln) * 768 + 256 + quad * 8);

    f32x4_t acc[4][4];
    #pragma unroll
    for (int i = 0; i < 4; ++i)
        #pragma unroll
        for (int j = 0; j < 4; ++j) { acc[i][j][0]=0.f; acc[i][j][1]=0.f; acc[i][j][2]=0.f; acc[i][j][3]=0.f; }
    #pragma unroll
    for (int i = 0; i < 4; ++i)
        #pragma unroll
        for (int j = 0; j < 4; ++j)
            acc[i][j] = __builtin_amdgcn_mfma_f32_16x16x32_bf16(qa[i], kb[j], acc[i][j], 0, 0, 0);

    const float scale = 0.17677669529663687f;
    int wi = win >> 3, wj = win & 7;
    int mjv = ln & 7;
    int regm[4], mi[4];
    #pragma unroll
    for (int j = 0; j < 4; ++j) {
        mi[j] = j * 2 + (ln >> 3);
        int hm = wi * 8 + mi[j], wm = wj * 8 + mjv;
        regm[j] = (hm < 56 ? 0 : (hm < 60 ? 1 : 2)) * 3 + (wm < 56 ? 0 : (wm < 60 ? 1 : 2));
    }
    float inv[4][4];
    #pragma unroll
    for (int i = 0; i < 4; ++i) {
        #pragma unroll
        for (int e = 0; e < 4; ++e) {
            int q = i * 16 + quad * 4 + e;
            int ti = q >> 3, tj = q & 7;
            int hn = wi * 8 + ti, wn = wj * 8 + tj;
            int regn = (hn < 56 ? 0 : (hn < 60 ? 1 : 2)) * 3 + (wn < 56 ? 0 : (wn < 60 ? 1 : 2));
            float sum = 0.f;
            #pragma unroll
            for (int j = 0; j < 4; ++j) {
                float bv = rs[((ti - mi[j] + 7) * 15 + (tj - mjv + 7)) * 8 + h];
                float sv = acc[i][j][e] * scale + bv + (regm[j] != regn ? -100.f : 0.f);
                float p = __expf(sv);
                sum += p;
                P[q * PR + j * 16 + ln] = f2bf(p);
            }
            #pragma unroll
            for (int off = 1; off < 16; off <<= 1) sum += __shfl_xor(sum, off, 64);
            inv[i][e] = 1.0f / sum;
        }
    }
    __syncthreads();

    bf16x8_t vb[2][2];
    #pragma unroll
    for (int jd = 0; jd < 2; ++jd)
        #pragma unroll
        for (int kc = 0; kc < 2; ++kc)
            vb[jd][kc] = *(const bf16x8_t*)&V[(jd * 16 + ln) * VR + kc * 32 + quad * 8];
    f32x4_t occ[4][2];
    #pragma unroll
    for (int i = 0; i < 4; ++i)
        #pragma unroll
        for (int jd = 0; jd < 2; ++jd) { occ[i][jd][0]=0.f; occ[i][jd][1]=0.f; occ[i][jd][2]=0.f; occ[i][jd][3]=0.f; }
    #pragma unroll
    for (int i = 0; i < 4; ++i) {
        #pragma unroll
        for (int kc = 0; kc < 2; ++kc) {
            bf16x8_t pf = *(const bf16x8_t*)&P[(i * 16 + ln) * PR + kc * 32 + quad * 8];
            occ[i][0] = __builtin_amdgcn_mfma_f32_16x16x32_bf16(pf, vb[0][kc], occ[i][0], 0, 0, 0);
            occ[i][1] = __builtin_amdgcn_mfma_f32_16x16x32_bf16(pf, vb[1][kc], occ[i][1], 0, 0, 0);
        }
    }

    unsigned short* cbase = ctx + (size_t)wg * 64 * 256 + h * 32;
    #pragma unroll
    for (int i = 0; i < 4; ++i)
        #pragma unroll
        for (int e = 0; e < 4; ++e) {
            int q = i * 16 + quad * 4 + e;
            #pragma unroll
            for (int jd = 0; jd < 2; ++jd)
                cbase[(size_t)q * 256 + jd * 16 + ln] = f2bf(occ[i][jd][e] * inv[i][e]);
        }
}

// ---------- launch ----------
extern "C" void kernel_launch(void* const* d_in, const int* in_sizes, int n_in,
                              void* d_out, int out_size, void* d_ws, size_t ws_size,
                              hipStream_t stream) {
    const float* hs   = (const float*)d_in[0];
    const float* ln1g = (const float*)d_in[1];
    const float* ln1b = (const float*)d_in[2];
    const float* wq   = (const float*)d_in[3];
    const float* bq   = (const float*)d_in[4];
    const float* wk   = (const float*)d_in[5];
    const float* bk   = (const float*)d_in[6];
    const float* wv   = (const float*)d_in[7];
    const float* bv   = (const float*)d_in[8];
    const float* relt = (const float*)d_in[9];
    const float* wo   = (const float*)d_in[10];
    const float* bo   = (const float*)d_in[11];
    const float* ln2g = (const float*)d_in[12];
    const float* ln2b = (const float*)d_in[13];
    const float* w1   = (const float*)d_in[14];
    const float* b1   = (const float*)d_in[15];
    const float* w2   = (const float*)d_in[16];
    const float* b2   = (const float*)d_in[17];
    float* out = (float*)d_out;

    const size_t NTOK = 32768;
    size_t off = 0;
    auto carve = [&](size_t bytes) { void* p = (char*)d_ws + off; off += (bytes + 255) & ~(size_t)255; return p; };
    unsigned short* wqkv_p = (unsigned short*)carve(768ull * 256 * 2);    // fragment order
    unsigned short* wo_p   = (unsigned short*)carve(65536ull * 2);
    unsigned short* w1p    = (unsigned short*)carve(262144ull * 2);
    unsigned short* w2p    = (unsigned short*)carve(262144ull * 2);
    float*          bqkv   = (float*)carve(768ull * 4);
    unsigned short* hiddenb= (unsigned short*)carve(NTOK * 256 * 2);  // bf16 residual state
    unsigned short* xw     = (unsigned short*)carve(NTOK * 256 * 2);  // also LN2 out
    unsigned short* qkvb   = (unsigned short*)carve(NTOK * 768 * 2);  // q|k|v
    unsigned short* cx     = (unsigned short*)carve(NTOK * 256 * 2);
    unsigned short* h1 = qkvb;   // MLP hidden [32768,1024] overlays qkv+cx (64MB)
    unsigned short* yb = xw;

    // 1) weights -> bf16 fragment order; biases packed [768] (block 384)
    cvt_all<<<385, 256, 0, stream>>>(wq, wk, wv, wo, w1, w2, bq, bk, bv, bqkv,
                                     wqkv_p, wo_p, w1p, w2p);

    // 2) LN1 + cyclic shift + window partition -> xw (bf16)
    ln_kernel<1, 0><<<8192, 256, 0, stream>>>(hs, ln1g, ln1b, xw);

    // 3) fused QKV projection
    gemm_tile<0, 256><<<dim3(256, 6), 256, 0, stream>>>(xw, wqkv_p, bqkv, 32768, 768, qkvb, nullptr, nullptr);

    // 4) windowed MFMA attention
    attn_mfma<<<1024, 256, 0, stream>>>(qkvb, relt, cx);

    // 5) out projection + window reverse + unshift + fp32 residual -> hiddenb (bf16)
    gemm_tile<2, 256><<<dim3(256, 2), 256, 0, stream>>>(cx, wo_p, bo, 32768, 256, hiddenb, nullptr, hs);

    // 6) LN2 (bf16 in) -> yb
    ln_kernel<0, 1><<<8192, 256, 0, stream>>>(hiddenb, ln2g, ln2b, yb);

    // 7) MLP up + GELU -> h1
    gemm_tile<1, 256><<<dim3(256, 8), 256, 0, stream>>>(yb, w1p, b1, 32768, 1024, h1, nullptr, nullptr);

    // 8) MLP down + bf16 residual -> out (fp32)
    gemm_tile<3, 1024><<<dim3(256, 2), 256, 0, stream>>>(h1, w2p, b2, 32768, 256, nullptr, out, hiddenb);
}